// Round 13
// baseline (464.108 us; speedup 1.0000x reference)
//
#include <hip/hip_runtime.h>

#define K_DIM 4096
#define N_DIM 4096
#define NT (K_DIM / 64)  // 64 K-tiles, 64 bytes deep each

typedef int v4i __attribute__((ext_vector_type(4)));

__device__ __forceinline__ void gload_lds16(const void* g, void* l) {
  __builtin_amdgcn_global_load_lds(
      (const __attribute__((address_space(1))) void*)g,
      (__attribute__((address_space(3))) void*)l, 16, 0, 0);
}

__device__ __forceinline__ int pack4(int4 w) {
  return (w.x & 0xff) | ((w.y & 0xff) << 8) | ((w.z & 0xff) << 16) | (w.w << 24);
}

// pack 4 int32 low-bytes into one int32 via 3x v_perm_b32
__device__ __forceinline__ int packb(int4 v) {
  int t0 = __builtin_amdgcn_perm((unsigned)v.y, (unsigned)v.x, 0x00000400u);
  int t1 = __builtin_amdgcn_perm((unsigned)v.w, (unsigned)v.z, 0x04000000u);
  return __builtin_amdgcn_perm((unsigned)t1, (unsigned)t0, 0x07060100u);
}

// int32 -> int8 pack for w only (x pack is fused into the GEMM)
__global__ __launch_bounds__(256) void pack_kernel(const int* __restrict__ src,
                                                   int4* __restrict__ dst, int n16) {
  int i = blockIdx.x * 256 + threadIdx.x;
  if (i >= n16) return;
  const int4* s = (const int4*)src + (size_t)i * 4;
  int4 w0 = s[0], w1 = s[1], w2 = s[2], w3 = s[3];
  int4 r;
  r.x = pack4(w0); r.y = pack4(w1); r.z = pack4(w2); r.w = pack4(w3);
  dst[i] = r;
}

// 256x256 tile, BK=64 bytes, 8 waves (2M x 4N), mfma_i32_16x16x64_i8.
// r8 skeleton (best measured: 146.5us, conflicts 0, deterministic) with the
// x-pack FUSED: A staged via reg (8x global_load_dwordx4 of int32 x at tile
// top -> v_perm pack -> 2x ds_write_b128 with WRITE-SIDE swizzle after MFMA
// group 3; HBM latency compiler-covered by the counted vmcnt it inserts
// before first use). B staged via gload_lds from pre-packed ws (r8-verbatim).
// LDS: 2-slot (A 2x16KB @0, B 2x16KB @32768) = 64 KB, 1-ahead.
// Race discipline (max conservative): NOTHING crosses a barrier -- end of
// tile does vmcnt(0) (issued ~2400cy earlier -> latency-covered) +
// lgkmcnt(0) + s_barrier. ds_writes of tile kt+1 land in slot (kt+1)&1,
// whose readers (tile kt-1) drained before the previous barrier.
// LDS swizzle (r8-verbatim, measured 0 conflicts): stored (row r, pos p)
// holds global chunk p ^ ((r>>1)&3). A: applied on ds_write address.
// B: inverse applied on global source (linear gload_lds dest), XOR on read.
__global__ __launch_bounds__(512, 2) void gemm256(
    const int* __restrict__ Xi, const char* __restrict__ Bp,
    const int* __restrict__ bias, const float* __restrict__ pa,
    const float* __restrict__ pb, int* __restrict__ out) {
  extern __shared__ __align__(16) char lds[];  // 65536 bytes

  const int tid = threadIdx.x;
  const int wid = tid >> 6;
  const int lane = tid & 63;

  // XCD-aware bijective swizzle (nwg = 512, % 8 == 0)
  const int nwg = gridDim.x;
  const int cpx = nwg >> 3;
  const int flat = blockIdx.x;
  const int wg = (flat & 7) * cpx + (flat >> 3);
  const int br = wg >> 4;  // 0..31 (M/256)
  const int bn = wg & 15;  // 0..15 (N/256)

  const int wr = wid >> 2;   // 0..1 -> M half (128 rows)
  const int wcol = wid & 3;  // 0..3 -> N quarter (64 cols)

  // --- A reg-staging: thread t -> row t>>1 (0..255), half t&1 (32 int32) ---
  const int arow = tid >> 1;
  const int ahalf = tid & 1;
  const int4* aBaseG = (const int4*)Xi + (size_t)(br * 256 + arow) * 1024 + ahalf * 8;
  // ds_write side: row arow, chunks c0=ahalf*2, c0+1; swizzle s=(arow>>1)&3
  const int aswz = (arow >> 1) & 3;
  const int wAddr0 = arow * 64 + (((ahalf * 2 + 0) ^ aswz) << 4);  // + slot*16384
  const int wAddr1 = arow * 64 + (((ahalf * 2 + 1) ^ aswz) << 4);

  // --- B staging (r8-verbatim): per-lane pre-swizzled global src, linear dest ---
  const int srow = tid >> 2;                        // 0..127
  const int schunk = (tid & 3) ^ ((tid >> 3) & 3);  // inverse-swizzled chunk
  const char* bSrc = Bp + (size_t)(bn * 256 + srow) * K_DIM + schunk * 16;

  auto stageB = [&](int kt) {
    const int s = (kt & 1) * 16384;
    const char* sbp = bSrc + kt * 64;
    char* db = lds + 32768 + s + tid * 16;
    gload_lds16(sbp, db);
    gload_lds16(sbp + (size_t)128 * K_DIM, db + 8192);
  };

  // --- fragment reads (r8-verbatim pattern, measured conflict-free) ---
  const int lrow = lane & 15;
  const int fchunk = lane >> 4;                   // 16B k-chunk 0..3
  const int rchunk = fchunk ^ ((lrow >> 1) & 3);  // swizzled slot chunk
  const int aOff = (wr * 128 + lrow) * 64 + rchunk * 16;           // + mi*1024 + slot
  const int bOff = 32768 + (wcol * 64 + lrow) * 64 + rchunk * 16;  // + ni*1024 + slot

  v4i acc[8][4];
  {
    v4i z = {0, 0, 0, 0};
#pragma unroll
    for (int mi = 0; mi < 8; ++mi)
#pragma unroll
      for (int ni = 0; ni < 4; ++ni) acc[mi][ni] = z;
  }

  // prologue: stage tile 0 (A via regs, B via gload_lds)
  {
    int4 al[8];
#pragma unroll
    for (int j = 0; j < 8; ++j) al[j] = aBaseG[0 * 16 + j];
    stageB(0);
    v4i P0 = {packb(al[0]), packb(al[1]), packb(al[2]), packb(al[3])};
    v4i P1 = {packb(al[4]), packb(al[5]), packb(al[6]), packb(al[7])};
    *(v4i*)&lds[wAddr0] = P0;
    *(v4i*)&lds[wAddr1] = P1;
    asm volatile("s_waitcnt vmcnt(0)" ::: "memory");
    asm volatile("s_waitcnt lgkmcnt(0)" ::: "memory");
    __builtin_amdgcn_s_barrier();
  }

  for (int kt = 0; kt < NT; ++kt) {
    const int sb = (kt & 1) * 16384;
    const int sbn = ((kt + 1) & 1) * 16384;

    // top: issue next tile's A loads (regs) + B gloads (LDS direct)
    int4 al[8];
    if (kt + 1 < NT) {
#pragma unroll
      for (int j = 0; j < 8; ++j) al[j] = aBaseG[(kt + 1) * 16 + j];
      stageB(kt + 1);
    }
    __builtin_amdgcn_sched_barrier(0);

    v4i bf[4], af[8];
    // head frag reads: all B + first two A
#pragma unroll
    for (int ni = 0; ni < 4; ++ni) bf[ni] = *(const v4i*)&lds[sb + bOff + ni * 1024];
    af[0] = *(const v4i*)&lds[sb + aOff + 0 * 1024];
    af[1] = *(const v4i*)&lds[sb + aOff + 1 * 1024];
    __builtin_amdgcn_sched_barrier(0);

    // interleaved: issue af[mi+2] ahead, 4 MFMA per group; pack A after grp 3
#pragma unroll
    for (int mi = 0; mi < 8; ++mi) {
      if (mi + 2 < 8) af[mi + 2] = *(const v4i*)&lds[sb + aOff + (mi + 2) * 1024];
      __builtin_amdgcn_sched_barrier(0);
      __builtin_amdgcn_s_setprio(1);
#pragma unroll
      for (int ni = 0; ni < 4; ++ni)
        acc[mi][ni] =
            __builtin_amdgcn_mfma_i32_16x16x64_i8(af[mi], bf[ni], acc[mi][ni], 0, 0, 0);
      __builtin_amdgcn_s_setprio(0);
      __builtin_amdgcn_sched_barrier(0);
      if (mi == 3 && kt + 1 < NT) {
        // pack + write A(kt+1); compiler inserts the counted vmcnt for al[]
        v4i P0 = {packb(al[0]), packb(al[1]), packb(al[2]), packb(al[3])};
        v4i P1 = {packb(al[4]), packb(al[5]), packb(al[6]), packb(al[7])};
        *(v4i*)&lds[sbn + wAddr0] = P0;
        *(v4i*)&lds[sbn + wAddr1] = P1;
        __builtin_amdgcn_sched_barrier(0);
      }
    }

    // boundary: drain everything (issued ~1 tile earlier -> covered), barrier
    if (kt + 1 < NT) {
      asm volatile("s_waitcnt vmcnt(0)" ::: "memory");
      asm volatile("s_waitcnt lgkmcnt(0)" ::: "memory");
      __builtin_amdgcn_s_barrier();
    }
  }

  // epilogue: y = round(alpha*acc + beta*bias), clamp, write int32
  const float alpha = *pa;
  const float beta = *pb;
  const int rg = lane >> 4;
#pragma unroll
  for (int ni = 0; ni < 4; ++ni) {
    const int n = bn * 256 + wcol * 64 + ni * 16 + lrow;
    const float bb2 = __fmul_rn(beta, (float)bias[n]);
#pragma unroll
    for (int mi = 0; mi < 8; ++mi) {
#pragma unroll
      for (int j = 0; j < 4; ++j) {
        const int m = br * 256 + wr * 128 + mi * 16 + rg * 4 + j;
        float y = __fadd_rn(__fmul_rn(alpha, (float)acc[mi][ni][j]), bb2);
        y = rintf(y);
        y = fminf(127.f, fmaxf(-128.f, y));
        out[(size_t)m * N_DIM + n] = (int)y;
      }
    }
  }
}

extern "C" void kernel_launch(void* const* d_in, const int* in_sizes, int n_in,
                              void* d_out, int out_size, void* d_ws, size_t ws_size,
                              hipStream_t stream) {
  const int* x = (const int*)d_in[0];       // [M,K] int8 values in int32
  const int* w = (const int*)d_in[1];       // [N,K] int8 values in int32
  const int* bias = (const int*)d_in[2];    // [N] int8 values in int32
  const float* pa = (const float*)d_in[3];  // alpha
  const float* pb = (const float*)d_in[4];  // beta
  int* out = (int*)d_out;

  const int M = in_sizes[0] / K_DIM;  // 8192
  const size_t wBytes = (size_t)N_DIM * K_DIM;

  char* wp = (char*)d_ws;
  const int n16w = (int)(wBytes / 16);
  pack_kernel<<<(n16w + 255) / 256, 256, 0, stream>>>(w, (int4*)wp, n16w);

  const int nwg = (M / 256) * (N_DIM / 256);  // 512
  hipFuncSetAttribute((const void*)gemm256,
                      hipFuncAttributeMaxDynamicSharedMemorySize, 65536);
  gemm256<<<nwg, 512, 65536, stream>>>(x, wp, bias, pa, pb, out);
}

// Round 14
// 194.971 us; speedup vs baseline: 2.3804x; 2.3804x over previous
//
#include <hip/hip_runtime.h>

#define K_DIM 4096
#define N_DIM 4096
#define NT (K_DIM / 64)  // 64 K-tiles, 64 bytes deep each

typedef int v4i __attribute__((ext_vector_type(4)));

__device__ __forceinline__ void gload_lds16(const void* g, void* l) {
  __builtin_amdgcn_global_load_lds(
      (const __attribute__((address_space(1))) void*)g,
      (__attribute__((address_space(3))) void*)l, 16, 0, 0);
}

__device__ __forceinline__ int pack4(int4 w) {
  return (w.x & 0xff) | ((w.y & 0xff) << 8) | ((w.z & 0xff) << 16) | (w.w << 24);
}

// fused int32 -> int8 pack for x and w (d_ws layout is contiguous: x then w)
__global__ __launch_bounds__(256) void pack_kernel(const int* __restrict__ x,
                                                   const int* __restrict__ w,
                                                   int4* __restrict__ dst, int n16x,
                                                   int n16) {
  int i = blockIdx.x * 256 + threadIdx.x;
  if (i >= n16) return;
  const int4* s = (i < n16x) ? ((const int4*)x + (size_t)i * 4)
                             : ((const int4*)w + (size_t)(i - n16x) * 4);
  int4 w0 = s[0], w1 = s[1], w2 = s[2], w3 = s[3];
  int4 r;
  r.x = pack4(w0); r.y = pack4(w1); r.z = pack4(w2); r.w = pack4(w3);
  dst[i] = r;
}

// 256x256 tile, BK=64 bytes, 8 waves (2M x 4N), mfma_i32_16x16x64_i8.
// LDS = 64 KB (2-slot dbuf: A 2x16KB + B 2x16KB) -> TWO blocks per CU in
// INDEPENDENT barrier domains (4 waves/SIMD total): when one block's waves
// sit at the boundary vmcnt(0)+barrier, the other block's waves feed the
// matrix pipe, and one block's epilogue overlaps the other's K-loop.
// r11 ran this with __launch_bounds__(512,4): the 128-VGPR cap spilled the
// 128-reg accumulator (VGPR_Count 64, FETCH 1.8GB, 939us) -- the theory
// was never tested. This round: (512,2) => compiler lands ~92-112 VGPR
// (r3/r12 precedent), <=128 => 4 waves/SIMD fit, 2x64KB LDS fits.
// Single-domain schedules (r3/r5/r6/r7/r8/r12) all pin MfmaUtil at 39-42%
// with neither pipe saturated: lockstep read-window/MFMA-window
// alternation. Grid=512 (256^2 tiles) keeps FETCH ~147MB (r9's 128^2
// variant tripled it -- tile size, not multi-block, was its failure).
// Sync cadence r5-deterministic: stage(kt+1) at tile TOP into the opposite
// slot (readers drained before the PREVIOUS boundary barrier), boundary
// vmcnt(0)+s_barrier (stage issued ~2000cy earlier -> drain latency-
// covered). All ds_reads consumed before the barrier (DS in-order).
// LDS swizzle (r8-verbatim, measured 0 conflicts): stored (row r, pos p)
// holds global chunk p ^ ((r>>1)&3); inverse applied on the global SOURCE
// (linear LDS dest required by global_load_lds), same XOR on ds_read.
__global__ __launch_bounds__(512, 2) void gemm256(
    const char* __restrict__ Ap, const char* __restrict__ Bp,
    const int* __restrict__ bias, const float* __restrict__ pa,
    const float* __restrict__ pb, int* __restrict__ out) {
  extern __shared__ __align__(16) char lds[];  // 65536 bytes

  const int tid = threadIdx.x;
  const int wid = tid >> 6;
  const int lane = tid & 63;

  // XCD-aware bijective swizzle (nwg = 512, % 8 == 0)
  const int nwg = gridDim.x;
  const int cpx = nwg >> 3;
  const int flat = blockIdx.x;
  const int wg = (flat & 7) * cpx + (flat >> 3);
  const int br = wg >> 4;  // 0..31 (M/256)
  const int bn = wg & 15;  // 0..15 (N/256)

  const int wr = wid >> 2;   // 0..1 -> M half (128 rows)
  const int wcol = wid & 3;  // 0..3 -> N quarter (64 cols)

  // --- staging (r8-verbatim): per-lane global src, linear LDS dest ---
  const int srow = tid >> 2;                        // 0..127
  const int schunk = (tid & 3) ^ ((tid >> 3) & 3);  // inverse-swizzled chunk
  const char* aSrc = Ap + (size_t)(br * 256 + srow) * K_DIM + schunk * 16;
  const char* bSrc = Bp + (size_t)(bn * 256 + srow) * K_DIM + schunk * 16;

  auto stage = [&](int kt) {
    const int s = (kt & 1) * 16384;
    const char* sa = aSrc + kt * 64;
    const char* sb2 = bSrc + kt * 64;
    char* da = lds + s + wid * 1024;
    char* db = lds + 32768 + s + wid * 1024;
    gload_lds16(sa, da);
    gload_lds16(sa + (size_t)128 * K_DIM, da + 8192);
    gload_lds16(sb2, db);
    gload_lds16(sb2 + (size_t)128 * K_DIM, db + 8192);
  };

  // --- fragment reads (r8-verbatim pattern, measured conflict-free) ---
  const int lrow = lane & 15;
  const int fchunk = lane >> 4;                   // 16B k-chunk 0..3
  const int rchunk = fchunk ^ ((lrow >> 1) & 3);  // swizzled slot chunk
  const int aOff = (wr * 128 + lrow) * 64 + rchunk * 16;           // + mi*1024 + slot
  const int bOff = 32768 + (wcol * 64 + lrow) * 64 + rchunk * 16;  // + ni*1024 + slot

  v4i acc[8][4];
  {
    v4i z = {0, 0, 0, 0};
#pragma unroll
    for (int mi = 0; mi < 8; ++mi)
#pragma unroll
      for (int ni = 0; ni < 4; ++ni) acc[mi][ni] = z;
  }

  // prologue: stage tile 0 only (2-slot, 1-ahead)
  stage(0);
  asm volatile("s_waitcnt vmcnt(0)" ::: "memory");
  __builtin_amdgcn_s_barrier();

  for (int kt = 0; kt < NT; ++kt) {
    const int sb = (kt & 1) * 16384;

    v4i bf[4], af[8];
    // head reads: all B + first two A
#pragma unroll
    for (int ni = 0; ni < 4; ++ni) bf[ni] = *(const v4i*)&lds[sb + bOff + ni * 1024];
    af[0] = *(const v4i*)&lds[sb + aOff + 0 * 1024];
    af[1] = *(const v4i*)&lds[sb + aOff + 1 * 1024];
    if (kt + 1 < NT) stage(kt + 1);  // opposite slot; readers drained last barrier
    __builtin_amdgcn_sched_barrier(0);

    // interleaved: issue af[mi+2] ahead, 4 MFMA per group
#pragma unroll
    for (int mi = 0; mi < 8; ++mi) {
      if (mi + 2 < 8) af[mi + 2] = *(const v4i*)&lds[sb + aOff + (mi + 2) * 1024];
      __builtin_amdgcn_sched_barrier(0);
#pragma unroll
      for (int ni = 0; ni < 4; ++ni)
        acc[mi][ni] =
            __builtin_amdgcn_mfma_i32_16x16x64_i8(af[mi], bf[ni], acc[mi][ni], 0, 0, 0);
      __builtin_amdgcn_sched_barrier(0);
    }

    // boundary: stage(kt+1) resident for all waves + slot-reuse fence
    asm volatile("s_waitcnt vmcnt(0)" ::: "memory");
    __builtin_amdgcn_s_barrier();
  }

  // epilogue: y = round(alpha*acc + beta*bias), clamp, write int32
  const float alpha = *pa;
  const float beta = *pb;
  const int rg = lane >> 4;
#pragma unroll
  for (int ni = 0; ni < 4; ++ni) {
    const int n = bn * 256 + wcol * 64 + ni * 16 + lrow;
    const float bb2 = __fmul_rn(beta, (float)bias[n]);
#pragma unroll
    for (int mi = 0; mi < 8; ++mi) {
#pragma unroll
      for (int j = 0; j < 4; ++j) {
        const int m = br * 256 + wr * 128 + mi * 16 + rg * 4 + j;
        float y = __fadd_rn(__fmul_rn(alpha, (float)acc[mi][ni][j]), bb2);
        y = rintf(y);
        y = fminf(127.f, fmaxf(-128.f, y));
        out[(size_t)m * N_DIM + n] = (int)y;
      }
    }
  }
}

extern "C" void kernel_launch(void* const* d_in, const int* in_sizes, int n_in,
                              void* d_out, int out_size, void* d_ws, size_t ws_size,
                              hipStream_t stream) {
  const int* x = (const int*)d_in[0];       // [M,K] int8 values in int32
  const int* w = (const int*)d_in[1];       // [N,K] int8 values in int32
  const int* bias = (const int*)d_in[2];    // [N] int8 values in int32
  const float* pa = (const float*)d_in[3];  // alpha
  const float* pb = (const float*)d_in[4];  // beta
  int* out = (int*)d_out;

  const int M = in_sizes[0] / K_DIM;  // 8192
  const size_t xBytes = (size_t)M * K_DIM;
  const size_t wBytes = (size_t)N_DIM * K_DIM;

  char* xp = (char*)d_ws;
  char* wp = xp + xBytes;
  const int n16x = (int)(xBytes / 16);
  const int n16 = (int)((xBytes + wBytes) / 16);
  pack_kernel<<<(n16 + 255) / 256, 256, 0, stream>>>(x, (const int*)d_in[1],
                                                     (int4*)xp, n16x, n16);

  const int nwg = (M / 256) * (N_DIM / 256);  // 512
  hipFuncSetAttribute((const void*)gemm256,
                      hipFuncAttributeMaxDynamicSharedMemorySize, 65536);
  gemm256<<<nwg, 512, 65536, stream>>>(xp, wp, bias, pa, pb, out);
}